// Round 1
// baseline (29.266 us; speedup 1.0000x reference)
//
#include <hip/hip_runtime.h>
#include <stdint.h>

typedef unsigned int u32;

#define FW   1024
#define NOUT 50
#define RPB  4      // rows (waves) per 256-thread block
#define CAP  320    // compacted-candidate capacity (n~203, +9 sigma safe)
#define SPL  5      // slots per lane (CAP/64)

// ---- DPP helpers (ctrl must be immediate) ----
#define DPP_UMAX_STEP(m, ctrl)                                                 \
  do {                                                                         \
    const u32 _t = (u32)__builtin_amdgcn_update_dpp(0, (int)(m), (ctrl),       \
                                                    0xf, 0xf, false);          \
    (m) = (m) > _t ? (m) : _t;                                                 \
  } while (0)
#define DPP_FMAX_STEP(m, ctrl)                                                 \
  do {                                                                         \
    const float _t = __uint_as_float((u32)__builtin_amdgcn_update_dpp(         \
        __float_as_int(m), __float_as_int(m), (ctrl), 0xf, 0xf, false));       \
    (m) = fmaxf((m), _t);                                                      \
  } while (0)
#define DPP_FMIN_STEP(m, ctrl)                                                 \
  do {                                                                         \
    const float _t = __uint_as_float((u32)__builtin_amdgcn_update_dpp(         \
        __float_as_int(m), __float_as_int(m), (ctrl), 0xf, 0xf, false));       \
    (m) = fminf((m), _t);                                                      \
  } while (0)
// inclusive add-scan step; row-masked bcast steps (round-7 lesson: 0xa/0xc)
#define DPP_SCAN_STEP(x, ctrl, rmask)                                          \
  do {                                                                         \
    const int _t = __builtin_amdgcn_update_dpp(0, (x), (ctrl), (rmask), 0xf,   \
                                               false);                         \
    (x) += _t;                                                                 \
  } while (0)

#define DPP_ALL6(OP, a)                                                        \
  OP(a, 0x111); OP(a, 0x112); OP(a, 0x114); OP(a, 0x118); OP(a, 0x142);        \
  OP(a, 0x143)

__device__ __forceinline__ u32 umax2(u32 a, u32 b) { return a > b ? a : b; }
__device__ __forceinline__ u32 umax3(u32 a, u32 b, u32 c) {
  return umax2(umax2(a, b), c);   // -> v_max3_u32
}

__global__ __launch_bounds__(256, 4) void nms1d_kernel(
    const float* __restrict__ logits,
    const float* __restrict__ delta,
    const int* __restrict__ iw_p,
    float* __restrict__ out_pos,   // [B,50,2]
    float* __restrict__ out_sc)    // [B,50]
{
  const int wave = threadIdx.x >> 6;
  const int lane = threadIdx.x & 63;
  const int b = blockIdx.x * RPB + wave;

  // per-wave SoA slots + 1 dump slot (branchless scatter target).
  __shared__ float2 s_kc[RPB][CAP + 1];
  __shared__ float2 s_pp[RPB][CAP + 1];
  float2* __restrict__ kc = s_kc[wave];
  float2* __restrict__ pp = s_pp[wave];

  const float hi = (float)(*iw_p) - 1.0f;   // img_width - 1

  const float* __restrict__ lrow = logits + (size_t)b * FW;
  const float* __restrict__ drow = delta  + (size_t)b * FW * 2;

  // ---- batch-issue ALL global loads upfront (one latency exposure).
  // VGPR_Count was stuck at 24 (compiler minimized regs -> serialized
  // load->use). 12 x float4 = 48 VGPRs; budget at (256,4) is 128.
  float4 xl0 = *(const float4*)(lrow + lane * 16 + 0);
  float4 xl1 = *(const float4*)(lrow + lane * 16 + 4);
  float4 xl2 = *(const float4*)(lrow + lane * 16 + 8);
  float4 xl3 = *(const float4*)(lrow + lane * 16 + 12);
  float4 dA0 = *(const float4*)(drow + lane * 32 + 0);
  float4 dB0 = *(const float4*)(drow + lane * 32 + 4);
  float4 dA1 = *(const float4*)(drow + lane * 32 + 8);
  float4 dB1 = *(const float4*)(drow + lane * 32 + 12);
  float4 dA2 = *(const float4*)(drow + lane * 32 + 16);
  float4 dB2 = *(const float4*)(drow + lane * 32 + 20);
  float4 dA3 = *(const float4*)(drow + lane * 32 + 24);
  float4 dB3 = *(const float4*)(drow + lane * 32 + 28);

  // ---- pass 1: sigmoid + per-lane valid count (lane owns f = lane*16+e) ----
  float sc[16];
  int v = 0;
  const float4 xls[4] = {xl0, xl1, xl2, xl3};
#pragma unroll
  for (int c = 0; c < 4; ++c) {
    const float xs[4] = {xls[c].x, xls[c].y, xls[c].z, xls[c].w};
#pragma unroll
    for (int j = 0; j < 4; ++j) {
      const float s = 1.0f / (1.0f + expf(-xs[j]));   // frozen: bit-matched ref
      sc[c * 4 + j] = s;
      v += (s >= 0.7f) ? 1 : 0;
    }
  }

  // inclusive prefix sum over lanes via DPP (canonical masked scan, proven r8)
  int incl = v;
  DPP_SCAN_STEP(incl, 0x111, 0xf);   // row_shr:1
  DPP_SCAN_STEP(incl, 0x112, 0xf);   // row_shr:2
  DPP_SCAN_STEP(incl, 0x114, 0xf);   // row_shr:4
  DPP_SCAN_STEP(incl, 0x118, 0xf);   // row_shr:8
  DPP_SCAN_STEP(incl, 0x142, 0xa);   // row_bcast:15 -> rows 1,3 only
  DPP_SCAN_STEP(incl, 0x143, 0xc);   // row_bcast:31 -> rows 2,3 only
  const int base = incl - v;
  const int n = __builtin_amdgcn_readlane(incl, 63);

  // ---- pass 2: positions/centers, BRANCHLESS compacted scatter, vmin/vmax --
  float vmin = INFINITY, vmax = -INFINITY;
  int q = base;
  const float4 dAs[4] = {dA0, dA1, dA2, dA3};
  const float4 dBs[4] = {dB0, dB1, dB2, dB3};
#pragma unroll
  for (int c = 0; c < 4; ++c) {
    const float dx[4] = {dAs[c].x, dAs[c].z, dBs[c].x, dBs[c].z};
    const float dy[4] = {dAs[c].y, dAs[c].w, dBs[c].y, dBs[c].w};
#pragma unroll
    for (int j = 0; j < 4; ++j) {
      const int e = c * 4 + j;
      const int f = lane * 16 + e;
      const float center = (float)f * 16.0f + 8.0f;   // (f+0.5)*16, exact
      float p0 = dx[j] * 16.0f + center;              // frozen: bit-matched ref
      float p1 = dy[j] * 16.0f + center;
      p0 = fminf(fmaxf(p0, 0.0f), hi);
      p1 = fminf(fmaxf(p1, 0.0f), hi);
      const float cc = (p0 + p1) * 0.5f;
      const float s = sc[e];
      const bool valid = (s >= 0.7f);
      vmin = valid ? fminf(vmin, cc) : vmin;          // cndmask, no exec write
      vmax = valid ? fmaxf(vmax, cc) : vmax;
      // branchless scatter: invalid (or overflow) elements hit dump slot CAP
      const int qd = (valid && q < CAP) ? q : CAP;
      // u32 key: s in [0.7,1] -> bits-diff fits 23 bits; <<9 | (511-q)
      // exact order w/ first-index tie-break (lower q = lower f).
      const u32 key = ((__float_as_uint(s) - 0x3F333333u) << 9) | (u32)(511 - q);
      kc[qd] = make_float2(__uint_as_float(key), cc);
      pp[qd] = make_float2(p0, p1);
      q += valid ? 1 : 0;
    }
  }

  // wave min/max via DPP (old=self identity; exact). Lane 63 holds the result.
  DPP_ALL6(DPP_FMIN_STEP, vmin);
  DPP_ALL6(DPP_FMAX_STEP, vmax);
  const float dt_part = (0.55f * (vmax - vmin)) / ((float)incl - 1.0f);
  const float dthresh = __uint_as_float(
      (u32)__builtin_amdgcn_readlane(__float_as_int(dt_part), 63));
  // n==1 -> NaN -> suppresses nothing (matches ref); n>=2 -> >=0 -> self-suppress

  // reload per-lane compacted slots (keys+cents) into registers (batched)
  const int nc = n < CAP ? n : CAP;
  u32 keys[SPL];
  float cents[SPL];
  {
    float2 sl[SPL];
#pragma unroll
    for (int k = 0; k < SPL; ++k) sl[k] = kc[lane * SPL + k];   // batch issue
#pragma unroll
    for (int k = 0; k < SPL; ++k) {
      const int q2 = lane * SPL + k;
      keys[k]  = (q2 < nc) ? __float_as_uint(sl[k].x) : 0u;
      cents[k] = sl[k].y;            // garbage for q2>=nc harmless (key==0)
    }
  }

  // ---- greedy NMS: 50 iters, branchless, FULLY UNROLLED ----
  // r9 change: winner center comes from REGISTERS (in-lane tournament carries
  // the cent; ballot+readlane fetches it cross-lane). The per-iteration
  // uniform-address ds_read (+lgkmcnt wait, ~130cy on the serial chain) is
  // gone; with only 4 waves/SIMD that latency was unhidden.
  u32 acckey = 0;        // lane j: winner key of output j (0 = none)
#pragma unroll
  for (int it = 0; it < NOUT; ++it) {
    // in-lane 5-slot tournament, carrying the center (selects run in
    // parallel with the DPP key chain below; off the critical path)
    bool g;
    g = keys[1] > keys[0];
    u32  mA = g ? keys[1]  : keys[0];
    float cA = g ? cents[1] : cents[0];
    g = keys[3] > keys[2];
    u32  mB = g ? keys[3]  : keys[2];
    float cB = g ? cents[3] : cents[2];
    g = mB > mA;
    mA = g ? mB : mA;
    cA = g ? cB : cA;
    g = keys[4] > mA;
    const u32   mk = g ? keys[4]  : mA;   // lane-local max key
    const float mc = g ? cents[4] : cA;   // its center

    // cross-lane max on key only (cheap 2-op DPP steps)
    u32 m = mk;
    DPP_UMAX_STEP(m, 0x111);
    DPP_UMAX_STEP(m, 0x112);
    DPP_UMAX_STEP(m, 0x114);
    DPP_UMAX_STEP(m, 0x118);
    DPP_UMAX_STEP(m, 0x142);
    DPP_UMAX_STEP(m, 0x143);
    const u32 best = (u32)__builtin_amdgcn_readlane((int)m, 63);   // SGPR

    // winner's center from the winner lane's register (keys unique -> the
    // ballot has exactly one bit unless best==0, where lane0 garbage is
    // harmless: all keys already 0, suppress is a no-op)
    const unsigned long long bal = __ballot(mk == best);
    const int wl = __ffsll((long long)bal) - 1;                    // SGPR
    const float sel_c = __uint_as_float(
        (u32)__builtin_amdgcn_readlane(__float_as_int(mc), wl));

    // lane `it` keeps the winner key (it is a LITERAL here: v_cmp + cndmask)
    acckey = (lane == it) ? best : acckey;

    // suppress |cent - sel_c| <= dthresh (includes self -> progress)
#pragma unroll
    for (int k = 0; k < SPL; ++k) {
      keys[k] = (fabsf(cents[k] - sel_c) <= dthresh) ? 0u : keys[k];
    }
  }

  // ---- epilogue: decode acckey, fetch p0/p1, single coalesced write ----
  if (lane < NOUT) {
    float p0 = 0.0f, p1 = 0.0f, s = 0.0f;
    if (acckey != 0u) {
      const int qw = 511 - (int)(acckey & 511u);    // valid -> qw < CAP
      const float2 sl = pp[qw];
      p0 = sl.x;
      p1 = sl.y;
      s  = __uint_as_float((acckey >> 9) + 0x3F333333u);   // exact score bits
    }
    float* __restrict__ orow_p = out_pos + (size_t)b * NOUT * 2;
    float* __restrict__ orow_s = out_sc  + (size_t)b * NOUT;
    *(float2*)(orow_p + lane * 2) = make_float2(p0, p1);
    orow_s[lane] = s;
  }
}

extern "C" void kernel_launch(void* const* d_in, const int* in_sizes, int n_in,
                              void* d_out, int out_size, void* d_ws, size_t ws_size,
                              hipStream_t stream) {
  const float* logits = (const float*)d_in[0];
  const float* delta  = (const float*)d_in[1];
  const int*   iw     = (const int*)d_in[2];
  const int B = in_sizes[0] / FW;            // 4096
  float* out_pos = (float*)d_out;                         // B*50*2
  float* out_sc  = (float*)d_out + (size_t)B * NOUT * 2;  // B*50
  nms1d_kernel<<<(B + RPB - 1) / RPB, RPB * 64, 0, stream>>>(logits, delta, iw, out_pos, out_sc);
}

// Round 2
// 26.336 us; speedup vs baseline: 1.1113x; 1.1113x over previous
//
#include <hip/hip_runtime.h>
#include <stdint.h>

typedef unsigned int u32;

#define FW   1024
#define NOUT 50
#define RPB  4      // rows (waves) per 256-thread block
#define CAP  320    // compacted-candidate capacity (n~203, +9 sigma safe)
#define SPL  5      // slots per lane (CAP/64)

// ---- DPP helpers (ctrl must be immediate) ----
#define DPP_FMAX_STEP(m, ctrl)                                                 \
  do {                                                                         \
    const float _t = __uint_as_float((u32)__builtin_amdgcn_update_dpp(         \
        __float_as_int(m), __float_as_int(m), (ctrl), 0xf, 0xf, false));       \
    (m) = fmaxf((m), _t);                                                      \
  } while (0)
#define DPP_FMIN_STEP(m, ctrl)                                                 \
  do {                                                                         \
    const float _t = __uint_as_float((u32)__builtin_amdgcn_update_dpp(         \
        __float_as_int(m), __float_as_int(m), (ctrl), 0xf, 0xf, false));       \
    (m) = fminf((m), _t);                                                      \
  } while (0)
// inclusive add-scan step; row-masked bcast steps (round-7 lesson: 0xa/0xc)
#define DPP_SCAN_STEP(x, ctrl, rmask)                                          \
  do {                                                                         \
    const int _t = __builtin_amdgcn_update_dpp(0, (x), (ctrl), (rmask), 0xf,   \
                                               false);                         \
    (x) += _t;                                                                 \
  } while (0)

#define DPP_ALL6(OP, a)                                                        \
  OP(a, 0x111); OP(a, 0x112); OP(a, 0x114); OP(a, 0x118); OP(a, 0x142);        \
  OP(a, 0x143)

__device__ __forceinline__ u32 umax2(u32 a, u32 b) { return a > b ? a : b; }
__device__ __forceinline__ u32 umax3(u32 a, u32 b, u32 c) {
  return umax2(umax2(a, b), c);   // -> v_max3_u32
}

// r10: fused-DPP 64-lane unsigned-max reduction. v_max_u32_dpp does
// max(dpp_fetch(src0), src1) in ONE instruction (vs mov_dpp+max = 2).
// bound_ctrl:0 (syntax) => invalid-lane fetch returns 0 = identity for umax,
// so row_bcast steps need no row_mask. s_nop 1 guards the VALU-write ->
// DPP-read hazard (hazard recognizer cannot see inside inline asm); trailing
// s_nop guards the compiler-emitted v_readlane that consumes %0 next.
#define DPP_UMAX_REDUCE64(m)                                                   \
  asm volatile(                                                                \
      "s_nop 1\n\t"                                                            \
      "v_max_u32_dpp %0, %0, %0 row_shr:1 row_mask:0xf bank_mask:0xf bound_ctrl:0\n\t" \
      "s_nop 1\n\t"                                                            \
      "v_max_u32_dpp %0, %0, %0 row_shr:2 row_mask:0xf bank_mask:0xf bound_ctrl:0\n\t" \
      "s_nop 1\n\t"                                                            \
      "v_max_u32_dpp %0, %0, %0 row_shr:4 row_mask:0xf bank_mask:0xf bound_ctrl:0\n\t" \
      "s_nop 1\n\t"                                                            \
      "v_max_u32_dpp %0, %0, %0 row_shr:8 row_mask:0xf bank_mask:0xf bound_ctrl:0\n\t" \
      "s_nop 1\n\t"                                                            \
      "v_max_u32_dpp %0, %0, %0 row_bcast:15 row_mask:0xf bank_mask:0xf bound_ctrl:0\n\t" \
      "s_nop 1\n\t"                                                            \
      "v_max_u32_dpp %0, %0, %0 row_bcast:31 row_mask:0xf bank_mask:0xf bound_ctrl:0\n\t" \
      "s_nop 1"                                                                \
      : "+v"(m))

__global__ __launch_bounds__(256, 4) void nms1d_kernel(
    const float* __restrict__ logits,
    const float* __restrict__ delta,
    const int* __restrict__ iw_p,
    float* __restrict__ out_pos,   // [B,50,2]
    float* __restrict__ out_sc)    // [B,50]
{
  const int wave = threadIdx.x >> 6;
  const int lane = threadIdx.x & 63;
  const int b = blockIdx.x * RPB + wave;

  // per-wave SoA slots + 1 dump slot (branchless scatter target).
  __shared__ float2 s_kc[RPB][CAP + 1];
  __shared__ float2 s_pp[RPB][CAP + 1];
  float2* __restrict__ kc = s_kc[wave];
  float2* __restrict__ pp = s_pp[wave];

  const float hi = (float)(*iw_p) - 1.0f;   // img_width - 1

  const float* __restrict__ lrow = logits + (size_t)b * FW;
  const float* __restrict__ drow = delta  + (size_t)b * FW * 2;

  // ---- batch-issue ALL global loads upfront (one latency exposure).
  float4 xl0 = *(const float4*)(lrow + lane * 16 + 0);
  float4 xl1 = *(const float4*)(lrow + lane * 16 + 4);
  float4 xl2 = *(const float4*)(lrow + lane * 16 + 8);
  float4 xl3 = *(const float4*)(lrow + lane * 16 + 12);
  float4 dA0 = *(const float4*)(drow + lane * 32 + 0);
  float4 dB0 = *(const float4*)(drow + lane * 32 + 4);
  float4 dA1 = *(const float4*)(drow + lane * 32 + 8);
  float4 dB1 = *(const float4*)(drow + lane * 32 + 12);
  float4 dA2 = *(const float4*)(drow + lane * 32 + 16);
  float4 dB2 = *(const float4*)(drow + lane * 32 + 20);
  float4 dA3 = *(const float4*)(drow + lane * 32 + 24);
  float4 dB3 = *(const float4*)(drow + lane * 32 + 28);

  // ---- pass 1: sigmoid + per-lane valid count (lane owns f = lane*16+e) ----
  float sc[16];
  int v = 0;
  const float4 xls[4] = {xl0, xl1, xl2, xl3};
#pragma unroll
  for (int c = 0; c < 4; ++c) {
    const float xs[4] = {xls[c].x, xls[c].y, xls[c].z, xls[c].w};
#pragma unroll
    for (int j = 0; j < 4; ++j) {
      const float s = 1.0f / (1.0f + expf(-xs[j]));   // frozen: bit-matched ref
      sc[c * 4 + j] = s;
      v += (s >= 0.7f) ? 1 : 0;
    }
  }

  // inclusive prefix sum over lanes via DPP (canonical masked scan, proven r8)
  int incl = v;
  DPP_SCAN_STEP(incl, 0x111, 0xf);   // row_shr:1
  DPP_SCAN_STEP(incl, 0x112, 0xf);   // row_shr:2
  DPP_SCAN_STEP(incl, 0x114, 0xf);   // row_shr:4
  DPP_SCAN_STEP(incl, 0x118, 0xf);   // row_shr:8
  DPP_SCAN_STEP(incl, 0x142, 0xa);   // row_bcast:15 -> rows 1,3 only
  DPP_SCAN_STEP(incl, 0x143, 0xc);   // row_bcast:31 -> rows 2,3 only
  const int base = incl - v;
  const int n = __builtin_amdgcn_readlane(incl, 63);

  // ---- pass 2: positions/centers, BRANCHLESS compacted scatter, vmin/vmax --
  float vmin = INFINITY, vmax = -INFINITY;
  int q = base;
  const float4 dAs[4] = {dA0, dA1, dA2, dA3};
  const float4 dBs[4] = {dB0, dB1, dB2, dB3};
#pragma unroll
  for (int c = 0; c < 4; ++c) {
    const float dx[4] = {dAs[c].x, dAs[c].z, dBs[c].x, dBs[c].z};
    const float dy[4] = {dAs[c].y, dAs[c].w, dBs[c].y, dBs[c].w};
#pragma unroll
    for (int j = 0; j < 4; ++j) {
      const int e = c * 4 + j;
      const int f = lane * 16 + e;
      const float center = (float)f * 16.0f + 8.0f;   // (f+0.5)*16, exact
      float p0 = dx[j] * 16.0f + center;              // frozen: bit-matched ref
      float p1 = dy[j] * 16.0f + center;
      p0 = fminf(fmaxf(p0, 0.0f), hi);
      p1 = fminf(fmaxf(p1, 0.0f), hi);
      const float cc = (p0 + p1) * 0.5f;
      const float s = sc[e];
      const bool valid = (s >= 0.7f);
      vmin = valid ? fminf(vmin, cc) : vmin;          // cndmask, no exec write
      vmax = valid ? fmaxf(vmax, cc) : vmax;
      // branchless scatter: invalid (or overflow) elements hit dump slot CAP
      const int qd = (valid && q < CAP) ? q : CAP;
      // u32 key: s in [0.7,1] -> bits-diff fits 23 bits; <<9 | (511-q)
      // exact order w/ first-index tie-break (lower q = lower f).
      const u32 key = ((__float_as_uint(s) - 0x3F333333u) << 9) | (u32)(511 - q);
      kc[qd] = make_float2(__uint_as_float(key), cc);
      pp[qd] = make_float2(p0, p1);
      q += valid ? 1 : 0;
    }
  }

  // wave min/max via DPP (old=self identity; exact). Lane 63 holds the result.
  DPP_ALL6(DPP_FMIN_STEP, vmin);
  DPP_ALL6(DPP_FMAX_STEP, vmax);
  const float dt_part = (0.55f * (vmax - vmin)) / ((float)incl - 1.0f);
  const float dthresh = __uint_as_float(
      (u32)__builtin_amdgcn_readlane(__float_as_int(dt_part), 63));
  // n==1 -> NaN -> suppresses nothing (matches ref); n>=2 -> >=0 -> self-suppress

  // reload per-lane compacted slots (keys+cents) into registers (batched)
  const int nc = n < CAP ? n : CAP;
  u32 keys[SPL];
  float cents[SPL];
  {
    float2 sl[SPL];
#pragma unroll
    for (int k = 0; k < SPL; ++k) sl[k] = kc[lane * SPL + k];   // batch issue
#pragma unroll
    for (int k = 0; k < SPL; ++k) {
      const int q2 = lane * SPL + k;
      keys[k]  = (q2 < nc) ? __float_as_uint(sl[k].x) : 0u;
      cents[k] = sl[k].y;            // garbage for q2>=nc harmless (key==0)
    }
  }

  // ---- greedy NMS: 50 iters, branchless, FULLY UNROLLED ----
  // r9 POST-MORTEM (do not redo): fetching sel_c from registers via
  // cent-carrying tournament + ballot/readlane REGRESSED 25.9->29.3us.
  // The loop is ISSUE-bound at 4 waves/SIMD: the uniform ds_read's latency
  // was hidden by other waves; its issue cost (1 ds_read) is far below the
  // ~10 VALU + VALU<->SALU hazards the register path added. Keep the LDS
  // winner fetch; spend effort on instruction COUNT instead (fused DPP).
  u32 acckey = 0;        // lane j: winner key of output j (0 = none)
#pragma unroll
  for (int it = 0; it < NOUT; ++it) {
    u32 m = umax3(keys[0], keys[1], keys[2]);
    m = umax3(m, keys[3], keys[4]);
    DPP_UMAX_REDUCE64(m);            // 6 fused v_max_u32_dpp (was 12 ops)
    const u32 best = (u32)__builtin_amdgcn_readlane((int)m, 63);   // SGPR

    // winner slot (scalar); clamp handles best==0 (keys all 0 -> harmless)
    const int qs  = 511 - (int)(best & 511u);
    const int qsc = qs < CAP ? qs : CAP - 1;
    const float sel_c = kc[qsc].y;      // uniform-addr ds_read broadcast

    // lane `it` keeps the winner key (it is a LITERAL here: v_cmp + cndmask)
    acckey = (lane == it) ? best : acckey;

    // suppress |cent - sel_c| <= dthresh (includes self -> progress)
#pragma unroll
    for (int k = 0; k < SPL; ++k) {
      keys[k] = (fabsf(cents[k] - sel_c) <= dthresh) ? 0u : keys[k];
    }
  }

  // ---- epilogue: decode acckey, fetch p0/p1, single coalesced write ----
  if (lane < NOUT) {
    float p0 = 0.0f, p1 = 0.0f, s = 0.0f;
    if (acckey != 0u) {
      const int qw = 511 - (int)(acckey & 511u);    // valid -> qw < CAP
      const float2 sl = pp[qw];
      p0 = sl.x;
      p1 = sl.y;
      s  = __uint_as_float((acckey >> 9) + 0x3F333333u);   // exact score bits
    }
    float* __restrict__ orow_p = out_pos + (size_t)b * NOUT * 2;
    float* __restrict__ orow_s = out_sc  + (size_t)b * NOUT;
    *(float2*)(orow_p + lane * 2) = make_float2(p0, p1);
    orow_s[lane] = s;
  }
}

extern "C" void kernel_launch(void* const* d_in, const int* in_sizes, int n_in,
                              void* d_out, int out_size, void* d_ws, size_t ws_size,
                              hipStream_t stream) {
  const float* logits = (const float*)d_in[0];
  const float* delta  = (const float*)d_in[1];
  const int*   iw     = (const int*)d_in[2];
  const int B = in_sizes[0] / FW;            // 4096
  float* out_pos = (float*)d_out;                         // B*50*2
  float* out_sc  = (float*)d_out + (size_t)B * NOUT * 2;  // B*50
  nms1d_kernel<<<(B + RPB - 1) / RPB, RPB * 64, 0, stream>>>(logits, delta, iw, out_pos, out_sc);
}